// Round 3
// baseline (10311.907 us; speedup 1.0000x reference)
//
#include <hip/hip_runtime.h>
#include <cstdint>
#include <cstddef>

#define B_   64
#define T_   512
#define E_   512
#define H_   1024
#define G4_  4096
#define KTOT 1536
#define NWG  256

typedef float f32x4 __attribute__((ext_vector_type(4)));
typedef int   i32x4 __attribute__((ext_vector_type(4)));

#define OFF_XE    ((size_t)0)
#define OFF_WC    (OFF_XE + (size_t)T_*B_*E_*2)     // 32 MB
#define OFF_BIAS  (OFF_WC + (size_t)G4_*KTOT*2)     // +12.6 MB
#define OFF_H0    (OFF_BIAS + (size_t)G4_*4)
#define OFF_H1    (OFF_H0 + (size_t)B_*H_*2)
#define OFF_FLAGS (OFF_H1 + (size_t)B_*H_*2)

__device__ __forceinline__ unsigned short f2b(float f) {
    unsigned u = __float_as_uint(f);
    return (unsigned short)((u + 0x7fffu + ((u >> 16) & 1u)) >> 16);  // RNE
}

// Permuted combined weights: permuted row p = gb*32 + q*8 + r  <->
// original gate row q*1024 + gb*8 + r (q: i,f,g,o). Row = [W_ih | W_hh], bf16.
__global__ void prep_w(const float* __restrict__ wih, const float* __restrict__ whh,
                       const float* __restrict__ bih, const float* __restrict__ bhh,
                       unsigned short* __restrict__ Wc, float* __restrict__ bp) {
    int p = blockIdx.x;
    int gb = p >> 5, q = (p >> 3) & 3, r = p & 7;
    int orig = q * H_ + gb * 8 + r;
    unsigned short* dst = Wc + (size_t)p * KTOT;
    const float* s1 = wih + (size_t)orig * E_;
    const float* s2 = whh + (size_t)orig * H_;
    int tx = threadIdx.x;
#pragma unroll
    for (int i = 0; i < 2; ++i) dst[tx + i*256] = f2b(s1[tx + i*256]);
#pragma unroll
    for (int i = 0; i < 4; ++i) dst[E_ + tx + i*256] = f2b(s2[tx + i*256]);
    if (tx == 0) bp[p] = bih[orig] + bhh[orig];
}

// xe[t][b][0:512] = bf16(emb[x[b][t]])
__global__ void prep_xe(const int* __restrict__ x, const float* __restrict__ emb,
                        unsigned short* __restrict__ xe) {
    int bid = blockIdx.x;
    int t = bid >> 6, b = bid & 63;
    int idx = x[b * T_ + t];
    const float* src = emb + (size_t)idx * E_;
    unsigned short* dst = xe + ((size_t)t * B_ + b) * E_;
    int tx = threadIdx.x;
    dst[tx] = f2b(src[tx]);
    dst[tx + 256] = f2b(src[tx + 256]);
}

__global__ void prep_h(const float* __restrict__ h0, unsigned short* __restrict__ hb) {
    int b = blockIdx.x;
#pragma unroll
    for (int i = 0; i < 4; ++i) {
        int j = threadIdx.x + i*256;
        hb[(size_t)b * H_ + j] = f2b(h0[(size_t)b * H_ + j]);
    }
}

// Persistent kernel, plain launch. 256 WGs (2 batch-blocks x 128 gate-blocks),
// 256 threads = 4 waves (mw = row half, kh = K half). Weights live in AGPRs
// for all T. Custom grid barrier: per-WG flag + agent-scope atomics +
// threadfence release/acquire (buffer_wbl2 / buffer_inv) for cross-XCD h.
__global__ __launch_bounds__(256, 1)
void lstm_pers(const unsigned short* __restrict__ xe,
               const unsigned short* __restrict__ Wc,
               const float* __restrict__ bp,
               const float* __restrict__ c0,
               unsigned short* __restrict__ hb0,
               unsigned short* __restrict__ hb1,
               float* __restrict__ out,
               int* __restrict__ flags) {
    __shared__ float gpart[2][32][33];

    const int tid = threadIdx.x;
    const int wg  = blockIdx.x;
    const int gb = wg & 127;
    const int bb = wg >> 7;
    const int gBase = gb << 5;
    const int w = tid >> 6, l = tid & 63;
    const int mw = w >> 1, kh = w & 1;
    const int lc = l & 15;              // lane col (B) / row (A)
    const int lk = (l >> 4) << 3;       // lane k-offset (elements)

    // ---- W fragments (held in AGPRs via "a" asm constraints below) ----
    i32x4 wreg0[24], wreg1[24];
    {
        const unsigned short* wp0 = Wc + (size_t)(gBase + lc) * KTOT + lk + kh * 768;
        const unsigned short* wp1 = wp0 + (size_t)16 * KTOT;
#pragma unroll
        for (int kk = 0; kk < 24; ++kk) {
            wreg0[kk] = *(const i32x4*)(wp0 + kk * 32);
            wreg1[kk] = *(const i32x4*)(wp1 + kk * 32);
        }
    }

    const int arow = (mw << 4) + lc;
    const int brow = (bb << 5) + arow;

    const int b_local = tid >> 3, r = tid & 7;
    const int bglob = (bb << 5) + b_local;
    const int hdim = (gb << 3) + r;
    float c = c0[(size_t)bglob * H_ + hdim];
    const float bi  = bp[gBase + r];
    const float bf_ = bp[gBase + 8 + r];
    const float bg  = bp[gBase + 16 + r];
    const float bo  = bp[gBase + 24 + r];

    for (int t = 0; t < T_; ++t) {
        const unsigned short* hr = (t & 1) ? hb1 : hb0;
        unsigned short* hw       = (t & 1) ? hb0 : hb1;

        const unsigned short* xp = xe + ((size_t)t * B_ + brow) * E_ + lk;
        const unsigned short* hp = hr + (size_t)brow * H_ + lk;

        i32x4 a[24];
        if (kh == 0) {
#pragma unroll
            for (int kk = 0; kk < 16; ++kk) a[kk] = *(const i32x4*)(xp + kk * 32);
#pragma unroll
            for (int kk = 16; kk < 24; ++kk) a[kk] = *(const i32x4*)(hp + (kk - 16) * 32);
        } else {
#pragma unroll
            for (int kk = 0; kk < 24; ++kk) a[kk] = *(const i32x4*)(hp + 256 + kk * 32);
        }

        f32x4 acc0 = {0.f, 0.f, 0.f, 0.f};
        f32x4 acc1 = {0.f, 0.f, 0.f, 0.f};
        // nops INSIDE the first MFMA asm: VALU acc-init -> MFMA SrcC hazard,
        // robust against compiler scheduling between asm statements.
        asm volatile("s_nop 3\n\tv_mfma_f32_16x16x32_bf16 %0, %1, %2, %0"
                     : "+v"(acc0) : "v"(a[0]), "a"(wreg0[0]));
        asm volatile("s_nop 3\n\tv_mfma_f32_16x16x32_bf16 %0, %1, %2, %0"
                     : "+v"(acc1) : "v"(a[0]), "a"(wreg1[0]));
#pragma unroll
        for (int kk = 1; kk < 24; ++kk) {
            asm volatile("v_mfma_f32_16x16x32_bf16 %0, %1, %2, %0"
                         : "+v"(acc0) : "v"(a[kk]), "a"(wreg0[kk]));
            asm volatile("v_mfma_f32_16x16x32_bf16 %0, %1, %2, %0"
                         : "+v"(acc1) : "v"(a[kk]), "a"(wreg1[kk]));
        }
        // MFMA -> read D hazard; "+v" accs force any acc read after this asm.
        asm volatile("s_nop 7\n\ts_nop 7\n\ts_nop 7"
                     : "+v"(acc0), "+v"(acc1) :: "memory");
        {
            const int grow = (mw << 4) + ((l >> 4) << 2);
#pragma unroll
            for (int j = 0; j < 4; ++j) {
                gpart[kh][grow + j][lc]      = acc0[j];
                gpart[kh][grow + j][16 + lc] = acc1[j];
            }
        }
        __syncthreads();

        // ---- LSTM cell; c stays in a register for all T ----
        {
            float xi = gpart[0][b_local][r]      + gpart[1][b_local][r]      + bi;
            float xf = gpart[0][b_local][8 + r]  + gpart[1][b_local][8 + r]  + bf_;
            float xg = gpart[0][b_local][16 + r] + gpart[1][b_local][16 + r] + bg;
            float xo = gpart[0][b_local][24 + r] + gpart[1][b_local][24 + r] + bo;
            float iv = 1.f / (1.f + __expf(-xi));
            float fv = 1.f / (1.f + __expf(-xf));
            float eg = __expf(2.f * fminf(fmaxf(xg, -15.f), 15.f));
            float gv = (eg - 1.f) / (eg + 1.f);
            float ov = 1.f / (1.f + __expf(-xo));
            c = fv * c + iv * gv;
            float ec = __expf(2.f * fminf(fmaxf(c, -15.f), 15.f));
            float th = (ec - 1.f) / (ec + 1.f);
            float hv = ov * th;
            __builtin_nontemporal_store(hv, &out[((size_t)bglob * T_ + t) * H_ + hdim]);
            hw[(size_t)bglob * H_ + hdim] = f2b(hv);
        }

        if (t == T_ - 1) break;   // no barrier needed after the last step

        // ---- grid barrier with cross-XCD coherence ----
        __syncthreads();                       // drains all WG stores (vmcnt 0)
        if (tid == 0) {
            __threadfence();                   // agent release: L2 writeback
            __hip_atomic_store(&flags[wg], t + 1, __ATOMIC_RELAXED,
                               __HIP_MEMORY_SCOPE_AGENT);
        }
        int dead = 0;
        {
            const int target = t + 1;
            unsigned spin = 0;
            while (__hip_atomic_load(&flags[tid], __ATOMIC_RELAXED,
                                     __HIP_MEMORY_SCOPE_AGENT) < target) {
                if (++spin > (1u << 21)) { dead = 1; break; }  // co-residency escape
            }
        }
        if (__syncthreads_or(dead)) break;     // uniform exit, no hang
        if (tid == 0) __threadfence();         // agent acquire: L2 invalidate
        __syncthreads();
    }
}

extern "C" void kernel_launch(void* const* d_in, const int* in_sizes, int n_in,
                              void* d_out, int out_size, void* d_ws, size_t ws_size,
                              hipStream_t stream) {
    const int*   x   = (const int*)  d_in[0];
    const float* emb = (const float*)d_in[1];
    const float* wih = (const float*)d_in[2];
    const float* whh = (const float*)d_in[3];
    const float* bih = (const float*)d_in[4];
    const float* bhh = (const float*)d_in[5];
    const float* h0  = (const float*)d_in[6];
    const float* c0  = (const float*)d_in[7];
    float* out = (float*)d_out;
    char* ws = (char*)d_ws;

    unsigned short* xe  = (unsigned short*)(ws + OFF_XE);
    unsigned short* Wc  = (unsigned short*)(ws + OFF_WC);
    float*          bp  = (float*)(ws + OFF_BIAS);
    unsigned short* hb0 = (unsigned short*)(ws + OFF_H0);
    unsigned short* hb1 = (unsigned short*)(ws + OFF_H1);
    int*            flg = (int*)(ws + OFF_FLAGS);

    (void)hipMemsetAsync(flg, 0, NWG * sizeof(int), stream);
    prep_w <<<dim3(G4_),   dim3(256), 0, stream>>>(wih, whh, bih, bhh, Wc, bp);
    prep_xe<<<dim3(B_*T_), dim3(256), 0, stream>>>(x, emb, xe);
    prep_h <<<dim3(B_),    dim3(256), 0, stream>>>(h0, hb0);

    lstm_pers<<<dim3(NWG), dim3(256), 0, stream>>>(xe, Wc, bp, c0, hb0, hb1, out, flg);
}

// Round 4
// 5326.448 us; speedup vs baseline: 1.9360x; 1.9360x over previous
//
#include <hip/hip_runtime.h>
#include <cstdint>
#include <cstddef>

#define B_   64
#define T_   512
#define E_   512
#define H_   1024
#define G4_  4096
#define KTOT 1536
#define NWG  256

typedef float f32x4 __attribute__((ext_vector_type(4)));
typedef int   i32x4 __attribute__((ext_vector_type(4)));

#define OFF_XE    ((size_t)0)
#define OFF_WC    (OFF_XE + (size_t)T_*B_*E_*2)     // 32 MB
#define OFF_BIAS  (OFF_WC + (size_t)G4_*KTOT*2)     // +12.6 MB
#define OFF_H0    (OFF_BIAS + (size_t)G4_*4)
#define OFF_FLAGS (OFF_H0 + (size_t)B_*H_*2)

__device__ __forceinline__ unsigned short f2b(float f) {
    unsigned u = __float_as_uint(f);
    return (unsigned short)((u + 0x7fffu + ((u >> 16) & 1u)) >> 16);  // RNE
}

// pack 8 f32 -> 8 bf16 (one MFMA A-frag) via v_cvt_pk_bf16_f32 (RNE)
__device__ __forceinline__ i32x4 cvt8(f32x4 lo, f32x4 hi) {
    unsigned p0, p1, p2, p3;
    asm("v_cvt_pk_bf16_f32 %0, %1, %2" : "=v"(p0) : "v"(lo[0]), "v"(lo[1]));
    asm("v_cvt_pk_bf16_f32 %0, %1, %2" : "=v"(p1) : "v"(lo[2]), "v"(lo[3]));
    asm("v_cvt_pk_bf16_f32 %0, %1, %2" : "=v"(p2) : "v"(hi[0]), "v"(hi[1]));
    asm("v_cvt_pk_bf16_f32 %0, %1, %2" : "=v"(p3) : "v"(hi[2]), "v"(hi[3]));
    i32x4 r = {(int)p0, (int)p1, (int)p2, (int)p3};
    return r;
}

// Permuted combined weights: permuted row p = gb*32 + q*8 + r  <->
// original gate row q*1024 + gb*8 + r (q: i,f,g,o). Row = [W_ih | W_hh], bf16.
__global__ void prep_w(const float* __restrict__ wih, const float* __restrict__ whh,
                       const float* __restrict__ bih, const float* __restrict__ bhh,
                       unsigned short* __restrict__ Wc, float* __restrict__ bp) {
    int p = blockIdx.x;
    int gb = p >> 5, q = (p >> 3) & 3, r = p & 7;
    int orig = q * H_ + gb * 8 + r;
    unsigned short* dst = Wc + (size_t)p * KTOT;
    const float* s1 = wih + (size_t)orig * E_;
    const float* s2 = whh + (size_t)orig * H_;
    int tx = threadIdx.x;
#pragma unroll
    for (int i = 0; i < 2; ++i) dst[tx + i*256] = f2b(s1[tx + i*256]);
#pragma unroll
    for (int i = 0; i < 4; ++i) dst[E_ + tx + i*256] = f2b(s2[tx + i*256]);
    if (tx == 0) bp[p] = bih[orig] + bhh[orig];
}

// xe[t][b][0:512] = bf16(emb[x[b][t]])
__global__ void prep_xe(const int* __restrict__ x, const float* __restrict__ emb,
                        unsigned short* __restrict__ xe) {
    int bid = blockIdx.x;
    int t = bid >> 6, b = bid & 63;
    int idx = x[b * T_ + t];
    const float* src = emb + (size_t)idx * E_;
    unsigned short* dst = xe + ((size_t)t * B_ + b) * E_;
    int tx = threadIdx.x;
    dst[tx] = f2b(src[tx]);
    dst[tx + 256] = f2b(src[tx + 256]);
}

__global__ void prep_h(const float* __restrict__ h0, unsigned short* __restrict__ hb) {
    int b = blockIdx.x;
#pragma unroll
    for (int i = 0; i < 4; ++i) {
        int j = threadIdx.x + i*256;
        hb[(size_t)b * H_ + j] = f2b(h0[(size_t)b * H_ + j]);
    }
}

// Persistent kernel, plain launch. 256 WGs = 2 independent 128-WG groups
// (bb = batch half); each WG: 32 gate-permuted rows, 256 threads = 4 waves
// (mw = row half, kh = K half). Weights in AGPRs for all T.
// h(t) travels through out[] (f32): producers bypass-store (agent atomic),
// consumers plain-cached-load fresh addresses -> no fences, no invalidates.
__global__ __launch_bounds__(256, 1)
void lstm_pers(const unsigned short* __restrict__ xe,
               const unsigned short* __restrict__ Wc,
               const float* __restrict__ bp,
               const float* __restrict__ c0,
               const unsigned short* __restrict__ hb0,
               float* __restrict__ out,
               int* __restrict__ flags) {
    __shared__ float gpart[2][32][33];

    const int tid = threadIdx.x;
    const int wg  = blockIdx.x;
    const int gb = wg & 127;
    const int bb = wg >> 7;
    const int gBase = gb << 5;
    const int w = tid >> 6, l = tid & 63;
    const int mw = w >> 1, kh = w & 1;
    const int lc = l & 15;              // lane col (B) / row (A)
    const int lk = (l >> 4) << 3;       // lane k-offset (elements)

    // ---- W fragments (held in AGPRs via "a" asm constraints below) ----
    i32x4 wreg0[24], wreg1[24];
    {
        const unsigned short* wp0 = Wc + (size_t)(gBase + lc) * KTOT + lk + kh * 768;
        const unsigned short* wp1 = wp0 + (size_t)16 * KTOT;
#pragma unroll
        for (int kk = 0; kk < 24; ++kk) {
            wreg0[kk] = *(const i32x4*)(wp0 + kk * 32);
            wreg1[kk] = *(const i32x4*)(wp1 + kk * 32);
        }
    }

    const int arow = (mw << 4) + lc;
    const int brow = (bb << 5) + arow;        // global batch row this lane loads

    const int b_local = tid >> 3, r = tid & 7;
    const int bglob = (bb << 5) + b_local;
    const int hdim = (gb << 3) + r;
    float c = c0[(size_t)bglob * H_ + hdim];
    const float bi  = bp[gBase + r];
    const float bf_ = bp[gBase + 8 + r];
    const float bg  = bp[gBase + 16 + r];
    const float bo  = bp[gBase + 24 + r];

    for (int t = 0; t < T_; ++t) {
        const unsigned short* xp = xe + ((size_t)t * B_ + brow) * E_ + lk;

        i32x4 a[24];
        if (t == 0) {
            const unsigned short* hp = hb0 + (size_t)brow * H_ + lk;
            if (kh == 0) {
#pragma unroll
                for (int kk = 0; kk < 16; ++kk) a[kk] = *(const i32x4*)(xp + kk * 32);
#pragma unroll
                for (int kk = 16; kk < 24; ++kk) a[kk] = *(const i32x4*)(hp + (kk - 16) * 32);
            } else {
#pragma unroll
                for (int kk = 0; kk < 24; ++kk) a[kk] = *(const i32x4*)(hp + 256 + kk * 32);
            }
        } else {
            // h(t-1) straight from out[:, t-1, :] (f32, plain cached loads)
            const float* hpf = out + ((size_t)brow * T_ + (t - 1)) * H_ + lk;
            if (kh == 0) {
#pragma unroll
                for (int kk = 0; kk < 16; ++kk) a[kk] = *(const i32x4*)(xp + kk * 32);
#pragma unroll
                for (int kk = 16; kk < 24; ++kk) {
                    f32x4 lo = *(const f32x4*)(hpf + (kk - 16) * 32);
                    f32x4 hi = *(const f32x4*)(hpf + (kk - 16) * 32 + 4);
                    a[kk] = cvt8(lo, hi);
                }
            } else {
#pragma unroll
                for (int kk = 0; kk < 24; ++kk) {
                    f32x4 lo = *(const f32x4*)(hpf + 256 + kk * 32);
                    f32x4 hi = *(const f32x4*)(hpf + 256 + kk * 32 + 4);
                    a[kk] = cvt8(lo, hi);
                }
            }
        }

        f32x4 acc0 = {0.f, 0.f, 0.f, 0.f};
        f32x4 acc1 = {0.f, 0.f, 0.f, 0.f};
        // s_nop inside every MFMA asm: covers VALU(acc-init/cvt) -> MFMA
        // SrcA/SrcC hazards regardless of compiler scheduling.
        asm volatile("s_nop 3\n\tv_mfma_f32_16x16x32_bf16 %0, %1, %2, %0"
                     : "+v"(acc0) : "v"(a[0]), "a"(wreg0[0]));
        asm volatile("s_nop 3\n\tv_mfma_f32_16x16x32_bf16 %0, %1, %2, %0"
                     : "+v"(acc1) : "v"(a[0]), "a"(wreg1[0]));
#pragma unroll
        for (int kk = 1; kk < 24; ++kk) {
            asm volatile("s_nop 1\n\tv_mfma_f32_16x16x32_bf16 %0, %1, %2, %0"
                         : "+v"(acc0) : "v"(a[kk]), "a"(wreg0[kk]));
            asm volatile("s_nop 1\n\tv_mfma_f32_16x16x32_bf16 %0, %1, %2, %0"
                         : "+v"(acc1) : "v"(a[kk]), "a"(wreg1[kk]));
        }
        asm volatile("s_nop 7\n\ts_nop 7\n\ts_nop 7"
                     : "+v"(acc0), "+v"(acc1) :: "memory");  // MFMA -> read D
        {
            const int grow = (mw << 4) + ((l >> 4) << 2);
#pragma unroll
            for (int j = 0; j < 4; ++j) {
                gpart[kh][grow + j][lc]      = acc0[j];
                gpart[kh][grow + j][16 + lc] = acc1[j];
            }
        }
        __syncthreads();

        // ---- LSTM cell; c stays in a register for all T ----
        {
            float xi = gpart[0][b_local][r]      + gpart[1][b_local][r]      + bi;
            float xf = gpart[0][b_local][8 + r]  + gpart[1][b_local][8 + r]  + bf_;
            float xg = gpart[0][b_local][16 + r] + gpart[1][b_local][16 + r] + bg;
            float xo = gpart[0][b_local][24 + r] + gpart[1][b_local][24 + r] + bo;
            float iv = 1.f / (1.f + __expf(-xi));
            float fv = 1.f / (1.f + __expf(-xf));
            float eg = __expf(2.f * fminf(fmaxf(xg, -15.f), 15.f));
            float gv = (eg - 1.f) / (eg + 1.f);
            float ov = 1.f / (1.f + __expf(-xo));
            c = fv * c + iv * gv;
            float ec = __expf(2.f * fminf(fmaxf(c, -15.f), 15.f));
            float th = (ec - 1.f) / (ec + 1.f);
            float hv = ov * th;
            // bypass store -> coherent point; this IS the h broadcast
            __hip_atomic_store(&out[((size_t)bglob * T_ + t) * H_ + hdim], hv,
                               __ATOMIC_RELAXED, __HIP_MEMORY_SCOPE_AGENT);
        }

        if (t == T_ - 1) break;

        // ---- fence-free grid barrier (two independent 128-WG groups) ----
        asm volatile("s_waitcnt vmcnt(0)" ::: "memory");   // out stores at L3
        __syncthreads();                                   // all waves drained
        if (tid == 0)
            __hip_atomic_store(&flags[wg], t + 1, __ATOMIC_RELAXED,
                               __HIP_MEMORY_SCOPE_AGENT);
        int dead = 0;
        if (w == 0) {                                      // wave 0 polls 128 flags
            const int tgt = t + 1;
            const int fb = bb << 7;
            unsigned spin = 0;
            for (;;) {
                int v0 = __hip_atomic_load(&flags[fb + l], __ATOMIC_RELAXED,
                                           __HIP_MEMORY_SCOPE_AGENT);
                int v1 = __hip_atomic_load(&flags[fb + 64 + l], __ATOMIC_RELAXED,
                                           __HIP_MEMORY_SCOPE_AGENT);
                if (v0 >= tgt && v1 >= tgt) break;
                __builtin_amdgcn_s_sleep(1);
                if (++spin > (1u << 20)) { dead = 1; break; }   // co-residency escape
            }
        }
        if (__syncthreads_or(dead)) break;                 // uniform exit, no hang
        asm volatile("" ::: "memory");   // next-step loads can't hoist above poll
    }
}

extern "C" void kernel_launch(void* const* d_in, const int* in_sizes, int n_in,
                              void* d_out, int out_size, void* d_ws, size_t ws_size,
                              hipStream_t stream) {
    const int*   x   = (const int*)  d_in[0];
    const float* emb = (const float*)d_in[1];
    const float* wih = (const float*)d_in[2];
    const float* whh = (const float*)d_in[3];
    const float* bih = (const float*)d_in[4];
    const float* bhh = (const float*)d_in[5];
    const float* h0  = (const float*)d_in[6];
    const float* c0  = (const float*)d_in[7];
    float* out = (float*)d_out;
    char* ws = (char*)d_ws;

    unsigned short* xe  = (unsigned short*)(ws + OFF_XE);
    unsigned short* Wc  = (unsigned short*)(ws + OFF_WC);
    float*          bp  = (float*)(ws + OFF_BIAS);
    unsigned short* hb0 = (unsigned short*)(ws + OFF_H0);
    int*            flg = (int*)(ws + OFF_FLAGS);

    (void)hipMemsetAsync(flg, 0, NWG * sizeof(int), stream);
    prep_w <<<dim3(G4_),   dim3(256), 0, stream>>>(wih, whh, bih, bhh, Wc, bp);
    prep_xe<<<dim3(B_*T_), dim3(256), 0, stream>>>(x, emb, xe);
    prep_h <<<dim3(B_),    dim3(256), 0, stream>>>(h0, hb0);

    lstm_pers<<<dim3(NWG), dim3(256), 0, stream>>>(xe, Wc, bp, c0, hb0, out, flg);
}

// Round 5
// 4727.781 us; speedup vs baseline: 2.1811x; 1.1266x over previous
//
#include <hip/hip_runtime.h>
#include <cstdint>
#include <cstddef>

#define B_   64
#define T_   512
#define E_   512
#define H_   1024
#define G4_  4096
#define KTOT 1536
#define NWG  256

typedef float f32x4 __attribute__((ext_vector_type(4)));
typedef int   i32x4 __attribute__((ext_vector_type(4)));

#define OFF_XE    ((size_t)0)
#define OFF_WC    (OFF_XE + (size_t)T_*B_*E_*2)     // 32 MB
#define OFF_BIAS  (OFF_WC + (size_t)G4_*KTOT*2)     // +12.6 MB
#define OFF_H0    (OFF_BIAS + (size_t)G4_*4)
#define OFF_FLAGS (OFF_H0 + (size_t)B_*H_*2)

__device__ __forceinline__ unsigned short f2b(float f) {
    unsigned u = __float_as_uint(f);
    return (unsigned short)((u + 0x7fffu + ((u >> 16) & 1u)) >> 16);  // RNE
}

// pack 8 f32 -> 8 bf16 (one MFMA A-frag) via v_cvt_pk_bf16_f32 (RNE)
__device__ __forceinline__ i32x4 cvt8(f32x4 lo, f32x4 hi) {
    unsigned p0, p1, p2, p3;
    asm("v_cvt_pk_bf16_f32 %0, %1, %2" : "=v"(p0) : "v"(lo[0]), "v"(lo[1]));
    asm("v_cvt_pk_bf16_f32 %0, %1, %2" : "=v"(p1) : "v"(lo[2]), "v"(lo[3]));
    asm("v_cvt_pk_bf16_f32 %0, %1, %2" : "=v"(p2) : "v"(hi[0]), "v"(hi[1]));
    asm("v_cvt_pk_bf16_f32 %0, %1, %2" : "=v"(p3) : "v"(hi[2]), "v"(hi[3]));
    i32x4 r = {(int)p0, (int)p1, (int)p2, (int)p3};
    return r;
}

// Permuted combined weights: permuted row p = gb*32 + q*8 + r  <->
// original gate row q*1024 + gb*8 + r (q: i,f,g,o). Row = [W_ih | W_hh], bf16.
__global__ void prep_w(const float* __restrict__ wih, const float* __restrict__ whh,
                       const float* __restrict__ bih, const float* __restrict__ bhh,
                       unsigned short* __restrict__ Wc, float* __restrict__ bp) {
    int p = blockIdx.x;
    int gb = p >> 5, q = (p >> 3) & 3, r = p & 7;
    int orig = q * H_ + gb * 8 + r;
    unsigned short* dst = Wc + (size_t)p * KTOT;
    const float* s1 = wih + (size_t)orig * E_;
    const float* s2 = whh + (size_t)orig * H_;
    int tx = threadIdx.x;
#pragma unroll
    for (int i = 0; i < 2; ++i) dst[tx + i*256] = f2b(s1[tx + i*256]);
#pragma unroll
    for (int i = 0; i < 4; ++i) dst[E_ + tx + i*256] = f2b(s2[tx + i*256]);
    if (tx == 0) bp[p] = bih[orig] + bhh[orig];
}

// xe[t][b][0:512] = bf16(emb[x[b][t]])
__global__ void prep_xe(const int* __restrict__ x, const float* __restrict__ emb,
                        unsigned short* __restrict__ xe) {
    int bid = blockIdx.x;
    int t = bid >> 6, b = bid & 63;
    int idx = x[b * T_ + t];
    const float* src = emb + (size_t)idx * E_;
    unsigned short* dst = xe + ((size_t)t * B_ + b) * E_;
    int tx = threadIdx.x;
    dst[tx] = f2b(src[tx]);
    dst[tx + 256] = f2b(src[tx + 256]);
}

__global__ void prep_h(const float* __restrict__ h0, unsigned short* __restrict__ hb) {
    int b = blockIdx.x;
#pragma unroll
    for (int i = 0; i < 4; ++i) {
        int j = threadIdx.x + i*256;
        hb[(size_t)b * H_ + j] = f2b(h0[(size_t)b * H_ + j]);
    }
}

// Persistent kernel, plain launch. 256 WGs = 2 independent 128-WG groups
// (bb = batch half). 256 threads = 4 waves (mw = row half, kh = K half).
// Balanced K-split per wave: 8 xe frags (k in [kh*256, kh*256+256)) +
// 16 h frags (d in [kh*512, kh*512+512)). xe frags for t+1 prefetched
// before the barrier; post-barrier each wave overlaps 16 xe-MFMAs with its
// 16 in-flight h loads. Weights in AGPRs for all T. h travels through out[]
// (agent-scope bypass stores; fresh-address cached loads -> no fences).
// Grid barrier = per-half monotonic counter (1 atomicAdd + 1-address poll).
__global__ __launch_bounds__(256, 1)
void lstm_pers(const unsigned short* __restrict__ xe,
               const unsigned short* __restrict__ Wc,
               const float* __restrict__ bp,
               const float* __restrict__ c0,
               const unsigned short* __restrict__ hb0,
               float* __restrict__ out,
               int* __restrict__ flags) {
    __shared__ float gpart[2][32][33];

    const int tid = threadIdx.x;
    const int wg  = blockIdx.x;
    const int gb = wg & 127;
    const int bb = wg >> 7;
    const int gBase = gb << 5;
    const int w = tid >> 6, l = tid & 63;
    const int mw = w >> 1, kh = w & 1;
    const int lc = l & 15;              // lane col (B) / row (A)
    const int lk = (l >> 4) << 3;       // lane k-offset (elements)

    // ---- W fragments (AGPRs via "a" asm constraints): frag j<8 = xe part,
    //      frag 8+j = h part, matching the balanced K-split below ----
    i32x4 wreg0[24], wreg1[24];
    {
        const unsigned short* wrow0 = Wc + (size_t)(gBase + lc) * KTOT;
        const unsigned short* wrow1 = wrow0 + (size_t)16 * KTOT;
#pragma unroll
        for (int j = 0; j < 8; ++j) {
            int k = (kh << 8) + j * 32 + lk;
            wreg0[j] = *(const i32x4*)(wrow0 + k);
            wreg1[j] = *(const i32x4*)(wrow1 + k);
        }
#pragma unroll
        for (int j = 0; j < 16; ++j) {
            int k = 512 + (kh << 9) + j * 32 + lk;
            wreg0[8 + j] = *(const i32x4*)(wrow0 + k);
            wreg1[8 + j] = *(const i32x4*)(wrow1 + k);
        }
    }

    const int arow = (mw << 4) + lc;
    const int brow = (bb << 5) + arow;        // global batch row this lane loads

    const int b_local = tid >> 3, r = tid & 7;
    const int bglob = (bb << 5) + b_local;
    const int hdim = (gb << 3) + r;
    float c = c0[(size_t)bglob * H_ + hdim];
    const float bi  = bp[gBase + r];
    const float bf_ = bp[gBase + 8 + r];
    const float bg  = bp[gBase + 16 + r];
    const float bo  = bp[gBase + 24 + r];

    int* ctr = &flags[bb << 4];               // one counter per batch-half

    i32x4 a[24];
    {   // t=0 xe frags (later steps prefetch them before the barrier)
        const unsigned short* xp = xe + ((size_t)brow) * E_ + (kh << 8) + lk;
#pragma unroll
        for (int j = 0; j < 8; ++j) a[j] = *(const i32x4*)(xp + j * 32);
    }

    for (int t = 0; t < T_; ++t) {
        // ---- h frags: 16 per wave, d in [kh*512, kh*512+512) ----
        if (t == 0) {
            const unsigned short* hp = hb0 + (size_t)brow * H_ + (kh << 9) + lk;
#pragma unroll
            for (int j = 0; j < 16; ++j) a[8 + j] = *(const i32x4*)(hp + j * 32);
        } else {
            const float* hpf = out + ((size_t)brow * T_ + (t - 1)) * H_ + (kh << 9) + lk;
#pragma unroll
            for (int j = 0; j < 16; ++j) {
                f32x4 lo = *(const f32x4*)(hpf + j * 32);
                f32x4 hi = *(const f32x4*)(hpf + j * 32 + 4);
                a[8 + j] = cvt8(lo, hi);
            }
        }

        f32x4 acc0 = {0.f, 0.f, 0.f, 0.f};
        f32x4 acc1 = {0.f, 0.f, 0.f, 0.f};
        // xe MFMAs first (operands already in regs) -> they run while the 16
        // h loads are still in flight. s_nop prefixes cover VALU->MFMA hazards.
        asm volatile("s_nop 3\n\tv_mfma_f32_16x16x32_bf16 %0, %1, %2, %0"
                     : "+v"(acc0) : "v"(a[0]), "a"(wreg0[0]));
        asm volatile("s_nop 3\n\tv_mfma_f32_16x16x32_bf16 %0, %1, %2, %0"
                     : "+v"(acc1) : "v"(a[0]), "a"(wreg1[0]));
#pragma unroll
        for (int j = 1; j < 24; ++j) {
            asm volatile("s_nop 1\n\tv_mfma_f32_16x16x32_bf16 %0, %1, %2, %0"
                         : "+v"(acc0) : "v"(a[j]), "a"(wreg0[j]));
            asm volatile("s_nop 1\n\tv_mfma_f32_16x16x32_bf16 %0, %1, %2, %0"
                         : "+v"(acc1) : "v"(a[j]), "a"(wreg1[j]));
        }
        asm volatile("s_nop 7\n\ts_nop 7\n\ts_nop 7"
                     : "+v"(acc0), "+v"(acc1) :: "memory");  // MFMA -> read D
        {
            const int grow = (mw << 4) + ((l >> 4) << 2);
#pragma unroll
            for (int j = 0; j < 4; ++j) {
                gpart[kh][grow + j][lc]      = acc0[j];
                gpart[kh][grow + j][16 + lc] = acc1[j];
            }
        }
        __syncthreads();

        // ---- LSTM cell; c stays in a register for all T ----
        {
            float xi = gpart[0][b_local][r]      + gpart[1][b_local][r]      + bi;
            float xf = gpart[0][b_local][8 + r]  + gpart[1][b_local][8 + r]  + bf_;
            float xg = gpart[0][b_local][16 + r] + gpart[1][b_local][16 + r] + bg;
            float xo = gpart[0][b_local][24 + r] + gpart[1][b_local][24 + r] + bo;
            float iv = 1.f / (1.f + __expf(-xi));
            float fv = 1.f / (1.f + __expf(-xf));
            float eg = __expf(2.f * fminf(fmaxf(xg, -15.f), 15.f));
            float gv = (eg - 1.f) / (eg + 1.f);
            float ov = 1.f / (1.f + __expf(-xo));
            c = fv * c + iv * gv;
            float ec = __expf(2.f * fminf(fmaxf(c, -15.f), 15.f));
            float th = (ec - 1.f) / (ec + 1.f);
            float hv = ov * th;
            // bypass store -> coherent point; this IS the h broadcast
            __hip_atomic_store(&out[((size_t)bglob * T_ + t) * H_ + hdim], hv,
                               __ATOMIC_RELAXED, __HIP_MEMORY_SCOPE_AGENT);
        }

        if (t == T_ - 1) break;

        // ---- prefetch next step's xe frags (overlaps drain + barrier) ----
        {
            const unsigned short* xp = xe + ((size_t)(t + 1) * B_ + brow) * E_
                                          + (kh << 8) + lk;
#pragma unroll
            for (int j = 0; j < 8; ++j) a[j] = *(const i32x4*)(xp + j * 32);
        }

        // ---- counter grid barrier (two independent 128-WG groups) ----
        asm volatile("s_waitcnt vmcnt(0)" ::: "memory");   // out stores at L3
        __syncthreads();                                   // all waves drained
        int dead = 0;
        if (tid == 0) {
            __hip_atomic_fetch_add(ctr, 1, __ATOMIC_RELAXED,
                                   __HIP_MEMORY_SCOPE_AGENT);
            const int tgt = (t + 1) << 7;                  // 128*(t+1), monotonic
            unsigned spin = 0;
            while (__hip_atomic_load(ctr, __ATOMIC_RELAXED,
                                     __HIP_MEMORY_SCOPE_AGENT) < tgt) {
                __builtin_amdgcn_s_sleep(1);
                if (++spin > (1u << 18)) { dead = 1; break; }  // escape, no hang
            }
        }
        if (__syncthreads_or(dead)) break;                 // uniform exit
        asm volatile("" ::: "memory");   // next-step loads can't hoist above poll
    }
}

extern "C" void kernel_launch(void* const* d_in, const int* in_sizes, int n_in,
                              void* d_out, int out_size, void* d_ws, size_t ws_size,
                              hipStream_t stream) {
    const int*   x   = (const int*)  d_in[0];
    const float* emb = (const float*)d_in[1];
    const float* wih = (const float*)d_in[2];
    const float* whh = (const float*)d_in[3];
    const float* bih = (const float*)d_in[4];
    const float* bhh = (const float*)d_in[5];
    const float* h0  = (const float*)d_in[6];
    const float* c0  = (const float*)d_in[7];
    float* out = (float*)d_out;
    char* ws = (char*)d_ws;

    unsigned short* xe  = (unsigned short*)(ws + OFF_XE);
    unsigned short* Wc  = (unsigned short*)(ws + OFF_WC);
    float*          bp  = (float*)(ws + OFF_BIAS);
    unsigned short* hb0 = (unsigned short*)(ws + OFF_H0);
    int*            flg = (int*)(ws + OFF_FLAGS);

    (void)hipMemsetAsync(flg, 0, 32 * sizeof(int), stream);
    prep_w <<<dim3(G4_),   dim3(256), 0, stream>>>(wih, whh, bih, bhh, Wc, bp);
    prep_xe<<<dim3(B_*T_), dim3(256), 0, stream>>>(x, emb, xe);
    prep_h <<<dim3(B_),    dim3(256), 0, stream>>>(h0, hb0);

    lstm_pers<<<dim3(NWG), dim3(256), 0, stream>>>(xe, Wc, bp, c0, hb0, out, flg);
}

// Round 7
// 3620.980 us; speedup vs baseline: 2.8478x; 1.3057x over previous
//
#include <hip/hip_runtime.h>
#include <cstdint>
#include <cstddef>

#define B_   64
#define T_   512
#define E_   512
#define H_   1024
#define G4_  4096
#define KTOT 1536
#define NWG  256

typedef float f32x4 __attribute__((ext_vector_type(4)));
typedef int   i32x4 __attribute__((ext_vector_type(4)));

#define OFF_XE    ((size_t)0)
#define OFF_WC    (OFF_XE + (size_t)T_*B_*E_*2)     // 32 MB
#define OFF_BIAS  (OFF_WC + (size_t)G4_*KTOT*2)     // +12.6 MB
#define OFF_H0    (OFF_BIAS + (size_t)G4_*4)
#define OFF_FLAGS (OFF_H0 + (size_t)B_*H_*2)

__device__ __forceinline__ unsigned short f2b(float f) {
    unsigned u = __float_as_uint(f);
    return (unsigned short)((u + 0x7fffu + ((u >> 16) & 1u)) >> 16);  // RNE
}

// pack 8 f32 -> 8 bf16 (one MFMA A-frag) via v_cvt_pk_bf16_f32 (RNE)
__device__ __forceinline__ i32x4 cvt8(f32x4 lo, f32x4 hi) {
    unsigned p0, p1, p2, p3;
    asm("v_cvt_pk_bf16_f32 %0, %1, %2" : "=v"(p0) : "v"(lo[0]), "v"(lo[1]));
    asm("v_cvt_pk_bf16_f32 %0, %1, %2" : "=v"(p1) : "v"(lo[2]), "v"(lo[3]));
    asm("v_cvt_pk_bf16_f32 %0, %1, %2" : "=v"(p2) : "v"(hi[0]), "v"(hi[1]));
    asm("v_cvt_pk_bf16_f32 %0, %1, %2" : "=v"(p3) : "v"(hi[2]), "v"(hi[3]));
    i32x4 r = {(int)p0, (int)p1, (int)p2, (int)p3};
    return r;
}

// Permuted combined weights: permuted row p = s*64 + q*16 + hl  <->
// original gate row q*1024 + s*16 + hl (q: i,f,g,o; s: 16-hdim block).
// Row = [W_ih | W_hh], bf16.
__global__ void prep_w(const float* __restrict__ wih, const float* __restrict__ whh,
                       const float* __restrict__ bih, const float* __restrict__ bhh,
                       unsigned short* __restrict__ Wc, float* __restrict__ bp) {
    int p = blockIdx.x;
    int s = p >> 6, q = (p >> 4) & 3, hl = p & 15;
    int orig = q * H_ + s * 16 + hl;
    unsigned short* dst = Wc + (size_t)p * KTOT;
    const float* s1 = wih + (size_t)orig * E_;
    const float* s2 = whh + (size_t)orig * H_;
    int tx = threadIdx.x;
#pragma unroll
    for (int i = 0; i < 2; ++i) dst[tx + i*256] = f2b(s1[tx + i*256]);
#pragma unroll
    for (int i = 0; i < 4; ++i) dst[E_ + tx + i*256] = f2b(s2[tx + i*256]);
    if (tx == 0) bp[p] = bih[orig] + bhh[orig];
}

// xe[t][b][0:512] = bf16(emb[x[b][t]])
__global__ void prep_xe(const int* __restrict__ x, const float* __restrict__ emb,
                        unsigned short* __restrict__ xe) {
    int bid = blockIdx.x;
    int t = bid >> 6, b = bid & 63;
    int idx = x[b * T_ + t];
    const float* src = emb + (size_t)idx * E_;
    unsigned short* dst = xe + ((size_t)t * B_ + b) * E_;
    int tx = threadIdx.x;
    dst[tx] = f2b(src[tx]);
    dst[tx + 256] = f2b(src[tx + 256]);
}

__global__ void prep_h(const float* __restrict__ h0, unsigned short* __restrict__ hb) {
    int b = blockIdx.x;
#pragma unroll
    for (int i = 0; i < 4; ++i) {
        int j = threadIdx.x + i*256;
        hb[(size_t)b * H_ + j] = f2b(h0[(size_t)b * H_ + j]);
    }
}

// Persistent kernel, plain launch. 256 WGs = 4 INDEPENDENT groups of 64 WGs
// (group g = blockIdx&3 owns batch rows [16g,16g+16); s = blockIdx>>2 picks
// 64 gate-cols). 256 threads = 4 waves (ch = col half, kh = K half).
// Balanced K-split per wave: 8 xe frags + 16 h frags. Weights in AGPRs all T.
// h travels through out[] (agent-scope bypass stores; fresh-address cached
// loads). Per-group barrier = monotonic agent counter (64 arrivals).
__global__ __launch_bounds__(256, 1)
void lstm_pers(const unsigned short* __restrict__ xe,
               const unsigned short* __restrict__ Wc,
               const float* __restrict__ bp,
               const float* __restrict__ c0,
               const unsigned short* __restrict__ hb0,
               float* __restrict__ out,
               int* __restrict__ flags) {
    __shared__ float gpart[2][16][68];

    const int tid = threadIdx.x;
    const int wg  = blockIdx.x;
    const int g   = wg & 3;              // batch group: rows [16g, 16g+16)
    const int s   = wg >> 2;             // gate block: permuted cols [64s, 64s+64)
    const int w = tid >> 6, l = tid & 63;
    const int ch = w >> 1, kh = w & 1;
    const int lc = l & 15;               // lane col (B) / row (A)
    const int lk = (l >> 4) << 3;        // lane k-offset (elements)

    // ---- W fragments (AGPRs via "a" asm constraints): frag j<8 = xe part,
    //      frag 8+j = h part, matching the balanced K-split below ----
    i32x4 wreg0[24], wreg1[24];
    {
        const unsigned short* wrow0 = Wc + (size_t)((s << 6) + (ch << 5) + lc) * KTOT;
        const unsigned short* wrow1 = wrow0 + (size_t)16 * KTOT;
#pragma unroll
        for (int j = 0; j < 8; ++j) {
            int k = (kh << 8) + j * 32 + lk;
            wreg0[j] = *(const i32x4*)(wrow0 + k);
            wreg1[j] = *(const i32x4*)(wrow1 + k);
        }
#pragma unroll
        for (int j = 0; j < 16; ++j) {
            int k = 512 + (kh << 9) + j * 32 + lk;
            wreg0[8 + j] = *(const i32x4*)(wrow0 + k);
            wreg1[8 + j] = *(const i32x4*)(wrow1 + k);
        }
    }

    const int brow = (g << 4) + lc;      // global batch row this lane loads

    // ---- cell ownership: thread (b_c, hl_c); c stays in a register all T ----
    const int b_c = tid >> 4, hl_c = tid & 15;
    const int bglob = (g << 4) + b_c;
    const int hdim = (s << 4) + hl_c;
    float c = c0[(size_t)bglob * H_ + hdim];
    const float bi  = bp[(s << 6) + hl_c];
    const float bf_ = bp[(s << 6) + 16 + hl_c];
    const float bg  = bp[(s << 6) + 32 + hl_c];
    const float bo  = bp[(s << 6) + 48 + hl_c];

    int* ctr = &flags[g << 5];           // one counter per group, 128 B apart

    i32x4 a[24];
    {   // t=0 xe frags (later steps prefetch them before the barrier)
        const unsigned short* xp = xe + ((size_t)brow) * E_ + (kh << 8) + lk;
#pragma unroll
        for (int j = 0; j < 8; ++j) a[j] = *(const i32x4*)(xp + j * 32);
    }

    for (int t = 0; t < T_; ++t) {
        // ---- h frags: 16 per wave, d in [kh*512, kh*512+512) ----
        if (t == 0) {
            const unsigned short* hp = hb0 + (size_t)brow * H_ + (kh << 9) + lk;
#pragma unroll
            for (int j = 0; j < 16; ++j) a[8 + j] = *(const i32x4*)(hp + j * 32);
        } else {
            const float* hpf = out + ((size_t)brow * T_ + (t - 1)) * H_ + (kh << 9) + lk;
#pragma unroll
            for (int j = 0; j < 16; ++j) {
                f32x4 lo = *(const f32x4*)(hpf + j * 32);
                f32x4 hi = *(const f32x4*)(hpf + j * 32 + 4);
                a[8 + j] = cvt8(lo, hi);
            }
        }

        f32x4 acc0 = {0.f, 0.f, 0.f, 0.f};
        f32x4 acc1 = {0.f, 0.f, 0.f, 0.f};
        // xe MFMAs first (operands already in regs) run while h loads are in
        // flight. s_nop prefixes cover VALU->MFMA SrcA/SrcC hazards.
        asm volatile("s_nop 3\n\tv_mfma_f32_16x16x32_bf16 %0, %1, %2, %0"
                     : "+v"(acc0) : "v"(a[0]), "a"(wreg0[0]));
        asm volatile("s_nop 3\n\tv_mfma_f32_16x16x32_bf16 %0, %1, %2, %0"
                     : "+v"(acc1) : "v"(a[0]), "a"(wreg1[0]));
#pragma unroll
        for (int j = 1; j < 24; ++j) {
            asm volatile("s_nop 1\n\tv_mfma_f32_16x16x32_bf16 %0, %1, %2, %0"
                         : "+v"(acc0) : "v"(a[j]), "a"(wreg0[j]));
            asm volatile("s_nop 1\n\tv_mfma_f32_16x16x32_bf16 %0, %1, %2, %0"
                         : "+v"(acc1) : "v"(a[j]), "a"(wreg1[j]));
        }
        asm volatile("s_nop 7\n\ts_nop 7\n\ts_nop 7"
                     : "+v"(acc0), "+v"(acc1) :: "memory");  // MFMA -> read D
        {
            const int grow = (l >> 4) << 2;
            const int cb = (ch << 5) + lc;
#pragma unroll
            for (int j = 0; j < 4; ++j) {
                gpart[kh][grow + j][cb]      = acc0[j];
                gpart[kh][grow + j][cb + 16] = acc1[j];
            }
        }
        __syncthreads();

        // ---- LSTM cell (one (b,hdim) per thread) ----
        {
            float xi = gpart[0][b_c][hl_c]      + gpart[1][b_c][hl_c]      + bi;
            float xf = gpart[0][b_c][16 + hl_c] + gpart[1][b_c][16 + hl_c] + bf_;
            float xg = gpart[0][b_c][32 + hl_c] + gpart[1][b_c][32 + hl_c] + bg;
            float xo = gpart[0][b_c][48 + hl_c] + gpart[1][b_c][48 + hl_c] + bo;
            float iv = 1.f / (1.f + __expf(-xi));
            float fv = 1.f / (1.f + __expf(-xf));
            float eg = __expf(2.f * fminf(fmaxf(xg, -15.f), 15.f));
            float gv = (eg - 1.f) / (eg + 1.f);
            float ov = 1.f / (1.f + __expf(-xo));
            c = fv * c + iv * gv;
            float ec = __expf(2.f * fminf(fmaxf(c, -15.f), 15.f));
            float th = (ec - 1.f) / (ec + 1.f);
            float hv = ov * th;
            // bypass store -> coherent point; this IS the h broadcast
            __hip_atomic_store(&out[((size_t)bglob * T_ + t) * H_ + hdim], hv,
                               __ATOMIC_RELAXED, __HIP_MEMORY_SCOPE_AGENT);
        }

        if (t == T_ - 1) break;

        // ---- prefetch next step's xe frags (overlaps drain + barrier) ----
        {
            const unsigned short* xp = xe + ((size_t)(t + 1) * B_ + brow) * E_
                                          + (kh << 8) + lk;
#pragma unroll
            for (int j = 0; j < 8; ++j) a[j] = *(const i32x4*)(xp + j * 32);
        }

        // ---- per-group counter barrier (4 independent 64-WG groups) ----
        asm volatile("s_waitcnt vmcnt(0)" ::: "memory");   // out stores at L3
        __syncthreads();                                   // all waves drained
        int dead = 0;
        if (tid == 0) {
            __hip_atomic_fetch_add(ctr, 1, __ATOMIC_RELAXED,
                                   __HIP_MEMORY_SCOPE_AGENT);
            const int tgt = (t + 1) << 6;                  // 64*(t+1), monotonic
            unsigned spin = 0;
            while (__hip_atomic_load(ctr, __ATOMIC_RELAXED,
                                     __HIP_MEMORY_SCOPE_AGENT) < tgt) {
                __builtin_amdgcn_s_sleep(1);
                if (++spin > (1u << 18)) { dead = 1; break; }  // escape, no hang
            }
        }
        if (__syncthreads_or(dead)) break;                 // uniform exit
        asm volatile("" ::: "memory");   // next-step loads can't hoist above poll
    }
}

extern "C" void kernel_launch(void* const* d_in, const int* in_sizes, int n_in,
                              void* d_out, int out_size, void* d_ws, size_t ws_size,
                              hipStream_t stream) {
    const int*   x   = (const int*)  d_in[0];
    const float* emb = (const float*)d_in[1];
    const float* wih = (const float*)d_in[2];
    const float* whh = (const float*)d_in[3];
    const float* bih = (const float*)d_in[4];
    const float* bhh = (const float*)d_in[5];
    const float* h0  = (const float*)d_in[6];
    const float* c0  = (const float*)d_in[7];
    float* out = (float*)d_out;
    char* ws = (char*)d_ws;

    unsigned short* xe  = (unsigned short*)(ws + OFF_XE);
    unsigned short* Wc  = (unsigned short*)(ws + OFF_WC);
    float*          bp  = (float*)(ws + OFF_BIAS);
    unsigned short* hb0 = (unsigned short*)(ws + OFF_H0);
    int*            flg = (int*)(ws + OFF_FLAGS);

    (void)hipMemsetAsync(flg, 0, 256 * sizeof(int), stream);
    prep_w <<<dim3(G4_),   dim3(256), 0, stream>>>(wih, whh, bih, bhh, Wc, bp);
    prep_xe<<<dim3(B_*T_), dim3(256), 0, stream>>>(x, emb, xe);
    prep_h <<<dim3(B_),    dim3(256), 0, stream>>>(h0, hb0);

    lstm_pers<<<dim3(NWG), dim3(256), 0, stream>>>(xe, Wc, bp, c0, hb0, out, flg);
}